// Round 5
// baseline (58.272 us; speedup 1.0000x reference)
//
#include <hip/hip_runtime.h>

#define CELL_F 50            // floats per cell: 2 boxes x (1 conf + 20 cls + 4 xywh)
#define LAMBDA_COORD 5.0f
#define LAMBDA_NOOBJ 0.5f
#define BLOCK 256
#define CPB 256                       // cells per block (grid divides exactly: 401408/256=1568)
#define TILE_V4 3200                  // float4 per tile = 51200 B LDS

__device__ __forceinline__ float iou8(float ax, float ay, float aw, float ah,
                                      float bx, float by, float bw, float bh) {
    float w = fminf(ax + aw * 0.5f, bx + bw * 0.5f) - fmaxf(ax - aw * 0.5f, bx - bw * 0.5f);
    float h = fminf(ay + ah * 0.5f, by + bh * 0.5f) - fmaxf(ay - ah * 0.5f, by - bh * 0.5f);
    float cross = w * h;
    float denom = aw * ah + bw * bh - cross;
    float iou = cross / denom;
    return (w <= 0.0f || h <= 0.0f) ? 0.0f : iou;
}

__global__ __launch_bounds__(BLOCK) void yolo_loss_partial(
        const float4* __restrict__ pr4, const float4* __restrict__ gt4,
        float* __restrict__ partial) {
    __shared__ float4 tile4[TILE_V4];
    float* tile = reinterpret_cast<float*>(tile4);
    const int tid = threadIdx.x;
    const int wid = tid >> 6;          // wave id (0..3)
    const int lane = tid & 63;
    const size_t base_v4 = (size_t)blockIdx.x * TILE_V4;

    // ---- issue pr -> LDS direct (global_load_lds, 16B/lane, linear dest) ----
    // per round: each wave moves 64*16B = 1KB; block moves 4KB; 3200 float4 = 12.5 rounds
    {
        const float4* gp = pr4 + base_v4 + (wid << 6) + lane;   // per-lane global src
        char* ldsbase = (char*)tile4 + (wid << 6) * 16;         // wave-uniform LDS base
        #pragma unroll
        for (int r = 0; r < 12; ++r) {
            __builtin_amdgcn_global_load_lds(
                (const __attribute__((address_space(1))) void*)(gp + r * 256),
                (__attribute__((address_space(3))) void*)(ldsbase + r * 4096),
                16, 0, 0);
        }
        if (wid < 2) {  // last half-round: waves 0,1 cover remaining 128 float4
            __builtin_amdgcn_global_load_lds(
                (const __attribute__((address_space(1))) void*)(gp + 12 * 256),
                (__attribute__((address_space(3))) void*)(ldsbase + 12 * 4096),
                16, 0, 0);
        }
    }

    // ---- issue gt -> registers (overlaps with pr loads; one drain at barrier) ----
    float4 greg[13];
    #pragma unroll
    for (int i = 0; i < 12; ++i) greg[i] = gt4[base_v4 + i * 256 + tid];
    if (tid < 128) greg[12] = gt4[base_v4 + 12 * 256 + tid];

    __syncthreads();   // vmcnt(0) drain: pr tile ready in LDS (gt regs landed too)

    // ---- unpack this thread's pr cell from LDS ----
    float P[CELL_F];
    {
        const float* src = tile + tid * CELL_F;   // 200B stride, 8B aligned
        #pragma unroll
        for (int i = 0; i < CELL_F / 2; ++i) {
            float2 v = *reinterpret_cast<const float2*>(src + 2 * i);
            P[2 * i] = v.x; P[2 * i + 1] = v.y;
        }
    }
    __syncthreads();

    // ---- write gt regs -> LDS (write-late: data already in regs, no latency) ----
    #pragma unroll
    for (int i = 0; i < 12; ++i) tile4[i * 256 + tid] = greg[i];
    if (tid < 128) tile4[12 * 256 + tid] = greg[12];
    __syncthreads();

    // ---- unpack this thread's gt cell ----
    float G[CELL_F];
    {
        const float* src = tile + tid * CELL_F;
        #pragma unroll
        for (int i = 0; i < CELL_F / 2; ++i) {
            float2 v = *reinterpret_cast<const float2*>(src + 2 * i);
            G[2 * i] = v.x; G[2 * i + 1] = v.y;
        }
    }

    // ---- per-cell YOLOv1 loss ----
    float acc;
    {
        float gc0 = G[0], gc1 = G[25];
        int obj_num = (gc0 != 0.0f ? 1 : 0) + (gc1 != 0.0f ? 1 : 0);
        float pc0 = P[0], pc1 = P[25];

        if (obj_num == 0) {
            acc = LAMBDA_NOOBJ * (pc0 + pc1);
        } else {
            float c0 = pc0 - 1.0f, c1 = pc1 - 1.0f;
            acc = c0 * c0 + c1 * c1;

            float iou00 = iou8(P[21], P[22], P[23], P[24], G[21], G[22], G[23], G[24]);
            float iou01 = iou8(P[21], P[22], P[23], P[24], G[46], G[47], G[48], G[49]);
            float iou10 = iou8(P[46], P[47], P[48], P[49], G[21], G[22], G[23], G[24]);
            float iou11 = iou8(P[46], P[47], P[48], P[49], G[46], G[47], G[48], G[49]);

            bool v1 = (obj_num > 1);
            float m01 = v1 ? iou01 : -1.0f;
            float m11 = v1 ? iou11 : -1.0f;
            int rsp0 = (m01 > iou00) ? 1 : 0;   // first-max argmax
            int rsp1 = (m11 > iou10) ? 1 : 0;

            float s00 = 0.0f, s01 = 0.0f, s10 = 0.0f, s11 = 0.0f;
            #pragma unroll
            for (int k = 0; k < 20; ++k) {
                float pk0 = P[1 + k], pk1 = P[26 + k];
                float gk0 = G[1 + k], gk1 = G[26 + k];
                float d;
                d = pk0 - gk0; s00 += d * d;
                d = pk0 - gk1; s01 += d * d;
                d = pk1 - gk0; s10 += d * d;
                d = pk1 - gk1; s11 += d * d;
            }
            float cls0 = (rsp0 ? s01 : s00) * (1.0f / 20.0f);
            float cls1 = (rsp1 ? s11 : s10) * (1.0f / 20.0f);

            {
                float rx = rsp0 ? G[46] : G[21];
                float ry = rsp0 ? G[47] : G[22];
                float rw = rsp0 ? G[48] : G[23];
                float rh = rsp0 ? G[49] : G[24];
                float dx = P[21] - rx, dy = P[22] - ry;
                float dw = sqrtf(P[23]) - sqrtf(rw);
                float dh = sqrtf(P[24]) - sqrtf(rh);
                acc += LAMBDA_COORD * (dx * dx + dy * dy + dw * dw + dh * dh) + cls0;
            }
            {
                float rx = rsp1 ? G[46] : G[21];
                float ry = rsp1 ? G[47] : G[22];
                float rw = rsp1 ? G[48] : G[23];
                float rh = rsp1 ? G[49] : G[24];
                float dx = P[46] - rx, dy = P[47] - ry;
                float dw = sqrtf(P[48]) - sqrtf(rw);
                float dh = sqrtf(P[49]) - sqrtf(rh);
                acc += LAMBDA_COORD * (dx * dx + dy * dy + dw * dw + dh * dh) + cls1;
            }
        }
    }

    // ---- block reduction ----
    #pragma unroll
    for (int off = 32; off > 0; off >>= 1) acc += __shfl_down(acc, off);
    __shared__ float wsum[BLOCK / 64];
    if (lane == 0) wsum[wid] = acc;
    __syncthreads();
    if (tid == 0) {
        partial[blockIdx.x] = wsum[0] + wsum[1] + wsum[2] + wsum[3];
    }
}

__global__ __launch_bounds__(BLOCK) void yolo_loss_final(
        const float* __restrict__ partial, int n, float* __restrict__ out,
        float inv_batch) {
    float acc = 0.0f;
    for (int i = threadIdx.x; i < n; i += BLOCK) acc += partial[i];
    #pragma unroll
    for (int off = 32; off > 0; off >>= 1) acc += __shfl_down(acc, off);
    __shared__ float wsum[BLOCK / 64];
    int lane = threadIdx.x & 63;
    int wid = threadIdx.x >> 6;
    if (lane == 0) wsum[wid] = acc;
    __syncthreads();
    if (threadIdx.x == 0) {
        out[0] = (wsum[0] + wsum[1] + wsum[2] + wsum[3]) * inv_batch;
    }
}

extern "C" void kernel_launch(void* const* d_in, const int* in_sizes, int n_in,
                              void* d_out, int out_size, void* d_ws, size_t ws_size,
                              hipStream_t stream) {
    const float4* pr4 = (const float4*)d_in[0];
    const float4* gt4 = (const float4*)d_in[1];
    float* out = (float*)d_out;
    float* partial = (float*)d_ws;

    int total_elems = in_sizes[0];            // 20,070,400
    int ncells = total_elems / CELL_F;        // 401,408 (divides 256 exactly)
    int batch = total_elems / 2450;           // 8192
    int blocks = ncells / CPB;                // 1568

    yolo_loss_partial<<<blocks, BLOCK, 0, stream>>>(pr4, gt4, partial);
    yolo_loss_final<<<1, BLOCK, 0, stream>>>(partial, blocks, out, 1.0f / (float)batch);
}

// Round 7
// 35.604 us; speedup vs baseline: 1.6367x; 1.6367x over previous
//
#include <hip/hip_runtime.h>

#define CELL_F 50            // floats per cell: 2 boxes x (1 conf + 20 cls + 4 xywh)
#define LAMBDA_COORD 5.0f
#define LAMBDA_NOOBJ 0.5f
#define BLOCK 256
#define WAVE_CELLS 64
#define WAVE_V4 (WAVE_CELLS * CELL_F / 4)   // 800 float4 per wave chunk
// per-wave LDS chunk = 12800 B; block total = 51200 B

__device__ __forceinline__ float iou8(float ax, float ay, float aw, float ah,
                                      float bx, float by, float bw, float bh) {
    float w = fminf(ax + aw * 0.5f, bx + bw * 0.5f) - fmaxf(ax - aw * 0.5f, bx - bw * 0.5f);
    float h = fminf(ay + ah * 0.5f, by + bh * 0.5f) - fmaxf(ay - ah * 0.5f, by - bh * 0.5f);
    float cross = w * h;
    float denom = aw * ah + bw * bh - cross;
    float iou = cross / denom;
    return (w <= 0.0f || h <= 0.0f) ? 0.0f : iou;
}

// stage one wave's 800-float4 chunk (64 cells) into wave-private LDS, async
__device__ __forceinline__ void stage_wave_chunk(const float4* gsrc, char* ldsbase, int lane) {
    #pragma unroll
    for (int r = 0; r < 12; ++r) {
        __builtin_amdgcn_global_load_lds(
            (const __attribute__((address_space(1))) void*)(gsrc + r * 64 + lane),
            (__attribute__((address_space(3))) void*)(ldsbase + r * 1024 + lane * 16),
            16, 0, 0);
    }
    if (lane < 32) {   // last half-round: 32 remaining float4
        __builtin_amdgcn_global_load_lds(
            (const __attribute__((address_space(1))) void*)(gsrc + 12 * 64 + lane),
            (__attribute__((address_space(3))) void*)(ldsbase + 12 * 1024 + lane * 16),
            16, 0, 0);
    }
}

__global__ __launch_bounds__(BLOCK) void yolo_loss_partial(
        const float4* __restrict__ pr4, const float4* __restrict__ gt4,
        float* __restrict__ partial) {
    __shared__ float4 tile4[4 * WAVE_V4];   // 51200 B
    const int tid = threadIdx.x;
    const int wid = tid >> 6;
    const int lane = tid & 63;

    const size_t wave_v4 = (size_t)blockIdx.x * (4 * WAVE_V4) + wid * WAVE_V4;
    float4* wtile4 = tile4 + wid * WAVE_V4;       // wave-private chunk
    float*  wtile  = reinterpret_cast<float*>(wtile4);
    char*   ldsb   = (char*)wtile4;

    // ---- stage pr chunk (async, wave-local; no block barrier anywhere) ----
    stage_wave_chunk(pr4 + wave_v4, ldsb, lane);
    asm volatile("s_waitcnt vmcnt(0)" ::: "memory");
    __builtin_amdgcn_sched_barrier(0);

    // ---- unpack this lane's pr cell ----
    float P[CELL_F];
    {
        const float* src = wtile + lane * CELL_F;    // 200B stride, 8B aligned
        #pragma unroll
        for (int i = 0; i < CELL_F / 2; ++i) {
            float2 v = *reinterpret_cast<const float2*>(src + 2 * i);
            P[2 * i] = v.x; P[2 * i + 1] = v.y;
        }
    }
    // all ds_reads must have returned before gt overwrites the buffer
    asm volatile("s_waitcnt lgkmcnt(0)" ::: "memory");
    __builtin_amdgcn_sched_barrier(0);

    // ---- stage gt chunk into the same wave-private buffer ----
    stage_wave_chunk(gt4 + wave_v4, ldsb, lane);
    asm volatile("s_waitcnt vmcnt(0)" ::: "memory");
    __builtin_amdgcn_sched_barrier(0);

    // ---- unpack this lane's gt cell ----
    float G[CELL_F];
    {
        const float* src = wtile + lane * CELL_F;
        #pragma unroll
        for (int i = 0; i < CELL_F / 2; ++i) {
            float2 v = *reinterpret_cast<const float2*>(src + 2 * i);
            G[2 * i] = v.x; G[2 * i + 1] = v.y;
        }
    }

    // ---- per-cell YOLOv1 loss ----
    float acc;
    {
        float gc0 = G[0], gc1 = G[25];
        int obj_num = (gc0 != 0.0f ? 1 : 0) + (gc1 != 0.0f ? 1 : 0);
        float pc0 = P[0], pc1 = P[25];

        if (obj_num == 0) {
            acc = LAMBDA_NOOBJ * (pc0 + pc1);
        } else {
            float c0 = pc0 - 1.0f, c1 = pc1 - 1.0f;
            acc = c0 * c0 + c1 * c1;

            float iou00 = iou8(P[21], P[22], P[23], P[24], G[21], G[22], G[23], G[24]);
            float iou01 = iou8(P[21], P[22], P[23], P[24], G[46], G[47], G[48], G[49]);
            float iou10 = iou8(P[46], P[47], P[48], P[49], G[21], G[22], G[23], G[24]);
            float iou11 = iou8(P[46], P[47], P[48], P[49], G[46], G[47], G[48], G[49]);

            bool v1 = (obj_num > 1);
            float m01 = v1 ? iou01 : -1.0f;
            float m11 = v1 ? iou11 : -1.0f;
            int rsp0 = (m01 > iou00) ? 1 : 0;   // first-max argmax
            int rsp1 = (m11 > iou10) ? 1 : 0;

            float s00 = 0.0f, s01 = 0.0f, s10 = 0.0f, s11 = 0.0f;
            #pragma unroll
            for (int k = 0; k < 20; ++k) {
                float pk0 = P[1 + k], pk1 = P[26 + k];
                float gk0 = G[1 + k], gk1 = G[26 + k];
                float d;
                d = pk0 - gk0; s00 += d * d;
                d = pk0 - gk1; s01 += d * d;
                d = pk1 - gk0; s10 += d * d;
                d = pk1 - gk1; s11 += d * d;
            }
            float cls0 = (rsp0 ? s01 : s00) * (1.0f / 20.0f);
            float cls1 = (rsp1 ? s11 : s10) * (1.0f / 20.0f);

            {
                float rx = rsp0 ? G[46] : G[21];
                float ry = rsp0 ? G[47] : G[22];
                float rw = rsp0 ? G[48] : G[23];
                float rh = rsp0 ? G[49] : G[24];
                float dx = P[21] - rx, dy = P[22] - ry;
                float dw = sqrtf(P[23]) - sqrtf(rw);
                float dh = sqrtf(P[24]) - sqrtf(rh);
                acc += LAMBDA_COORD * (dx * dx + dy * dy + dw * dw + dh * dh) + cls0;
            }
            {
                float rx = rsp1 ? G[46] : G[21];
                float ry = rsp1 ? G[47] : G[22];
                float rw = rsp1 ? G[48] : G[23];
                float rh = rsp1 ? G[49] : G[24];
                float dx = P[46] - rx, dy = P[47] - ry;
                float dw = sqrtf(P[48]) - sqrtf(rw);
                float dh = sqrtf(P[49]) - sqrtf(rh);
                acc += LAMBDA_COORD * (dx * dx + dy * dy + dw * dw + dh * dh) + cls1;
            }
        }
    }

    // ---- wave-local reduction; per-wave partial (no block barrier) ----
    #pragma unroll
    for (int off = 32; off > 0; off >>= 1) acc += __shfl_down(acc, off);
    if (lane == 0) partial[blockIdx.x * 4 + wid] = acc;
}

__global__ __launch_bounds__(BLOCK) void yolo_loss_final(
        const float* __restrict__ partial, int n, float* __restrict__ out,
        float inv_batch) {
    float acc = 0.0f;
    for (int i = threadIdx.x; i < n; i += BLOCK) acc += partial[i];
    #pragma unroll
    for (int off = 32; off > 0; off >>= 1) acc += __shfl_down(acc, off);
    __shared__ float wsum[BLOCK / 64];
    int lane = threadIdx.x & 63;
    int wid = threadIdx.x >> 6;
    if (lane == 0) wsum[wid] = acc;
    __syncthreads();
    if (threadIdx.x == 0) {
        out[0] = (wsum[0] + wsum[1] + wsum[2] + wsum[3]) * inv_batch;
    }
}

extern "C" void kernel_launch(void* const* d_in, const int* in_sizes, int n_in,
                              void* d_out, int out_size, void* d_ws, size_t ws_size,
                              hipStream_t stream) {
    const float4* pr4 = (const float4*)d_in[0];
    const float4* gt4 = (const float4*)d_in[1];
    float* out = (float*)d_out;
    float* partial = (float*)d_ws;

    int total_elems = in_sizes[0];            // 20,070,400
    int ncells = total_elems / CELL_F;        // 401,408 (divides 256 exactly)
    int batch = total_elems / 2450;           // 8192
    int blocks = ncells / 256;                // 1568
    int npartial = blocks * 4;                // per-wave partials

    yolo_loss_partial<<<blocks, BLOCK, 0, stream>>>(pr4, gt4, partial);
    yolo_loss_final<<<1, BLOCK, 0, stream>>>(partial, npartial, out, 1.0f / (float)batch);
}

// Round 8
// 33.160 us; speedup vs baseline: 1.7573x; 1.0737x over previous
//
#include <hip/hip_runtime.h>

#define CELL_F 50            // floats per cell: 2 boxes x (1 conf + 20 cls + 4 xywh)
#define LAMBDA_COORD 5.0f
#define LAMBDA_NOOBJ 0.5f
#define TILE_CELLS 64        // one tile = one wave's 64 cells
#define TILE_V4 800          // float4 per tensor per tile (64*50/4)
#define NBLOCKS 1536         // 6 blocks/CU * 256 CU; LDS 25.6KB -> 6 resident/CU

__device__ __forceinline__ float iou8(float ax, float ay, float aw, float ah,
                                      float bx, float by, float bw, float bh) {
    float w = fminf(ax + aw * 0.5f, bx + bw * 0.5f) - fmaxf(ax - aw * 0.5f, bx - bw * 0.5f);
    float h = fminf(ay + ah * 0.5f, by + bh * 0.5f) - fmaxf(ay - ah * 0.5f, by - bh * 0.5f);
    float cross = w * h;
    float denom = aw * ah + bw * bh - cross;
    float iou = cross / denom;
    return (w <= 0.0f || h <= 0.0f) ? 0.0f : iou;
}

// issue one tile's pr+gt loads (26 global_load_lds, async, no waits)
__device__ __forceinline__ void issue_tile(const float4* __restrict__ pr4,
                                           const float4* __restrict__ gt4,
                                           int tile, float4* buf4, int lane) {
    const float4* ps = pr4 + (size_t)tile * TILE_V4;
    const float4* gs = gt4 + (size_t)tile * TILE_V4;
    char* A = (char*)buf4;                    // pr half: 12800 B
    char* B = (char*)(buf4 + TILE_V4);        // gt half: 12800 B
    #pragma unroll
    for (int r = 0; r < 12; ++r) {
        __builtin_amdgcn_global_load_lds(
            (const __attribute__((address_space(1))) void*)(ps + r * 64 + lane),
            (__attribute__((address_space(3))) void*)(A + r * 1024 + lane * 16),
            16, 0, 0);
    }
    if (lane < 32) {
        __builtin_amdgcn_global_load_lds(
            (const __attribute__((address_space(1))) void*)(ps + 768 + lane),
            (__attribute__((address_space(3))) void*)(A + 12288 + lane * 16),
            16, 0, 0);
    }
    #pragma unroll
    for (int r = 0; r < 12; ++r) {
        __builtin_amdgcn_global_load_lds(
            (const __attribute__((address_space(1))) void*)(gs + r * 64 + lane),
            (__attribute__((address_space(3))) void*)(B + r * 1024 + lane * 16),
            16, 0, 0);
    }
    if (lane < 32) {
        __builtin_amdgcn_global_load_lds(
            (const __attribute__((address_space(1))) void*)(gs + 768 + lane),
            (__attribute__((address_space(3))) void*)(B + 12288 + lane * 16),
            16, 0, 0);
    }
}

__global__ __launch_bounds__(64) void yolo_loss_partial(
        const float4* __restrict__ pr4, const float4* __restrict__ gt4,
        float* __restrict__ partial, int ntiles) {
    __shared__ float4 buf4[2 * TILE_V4];      // A:pr, B:gt = 25600 B
    float* bufA = reinterpret_cast<float*>(buf4);
    float* bufB = reinterpret_cast<float*>(buf4 + TILE_V4);
    const int lane = threadIdx.x;
    const int stride = gridDim.x;

    // prologue: first tile's loads in flight
    issue_tile(pr4, gt4, blockIdx.x, buf4, lane);

    float acc = 0.0f;
    for (int tile = blockIdx.x; tile < ntiles; tile += stride) {
        asm volatile("s_waitcnt vmcnt(0)" ::: "memory");   // tile's 26 loads landed
        __builtin_amdgcn_sched_barrier(0);

        // unpack this lane's cell from both buffers
        float P[CELL_F], G[CELL_F];
        {
            const float* sp = bufA + lane * CELL_F;        // 200B stride, 8B aligned
            const float* sg = bufB + lane * CELL_F;
            #pragma unroll
            for (int i = 0; i < CELL_F / 2; ++i) {
                float2 v = *reinterpret_cast<const float2*>(sp + 2 * i);
                P[2 * i] = v.x; P[2 * i + 1] = v.y;
                float2 u = *reinterpret_cast<const float2*>(sg + 2 * i);
                G[2 * i] = u.x; G[2 * i + 1] = u.y;
            }
        }
        asm volatile("s_waitcnt lgkmcnt(0)" ::: "memory"); // reads done; bufs free
        __builtin_amdgcn_sched_barrier(0);

        // prefetch next tile: its HBM latency hides under compute below
        int next = tile + stride;
        if (next < ntiles) issue_tile(pr4, gt4, next, buf4, lane);

        // ---- per-cell YOLOv1 loss ----
        float gc0 = G[0], gc1 = G[25];
        int obj_num = (gc0 != 0.0f ? 1 : 0) + (gc1 != 0.0f ? 1 : 0);
        float pc0 = P[0], pc1 = P[25];

        if (obj_num == 0) {
            acc += LAMBDA_NOOBJ * (pc0 + pc1);
        } else {
            float c0 = pc0 - 1.0f, c1 = pc1 - 1.0f;
            acc += c0 * c0 + c1 * c1;

            float iou00 = iou8(P[21], P[22], P[23], P[24], G[21], G[22], G[23], G[24]);
            float iou01 = iou8(P[21], P[22], P[23], P[24], G[46], G[47], G[48], G[49]);
            float iou10 = iou8(P[46], P[47], P[48], P[49], G[21], G[22], G[23], G[24]);
            float iou11 = iou8(P[46], P[47], P[48], P[49], G[46], G[47], G[48], G[49]);

            bool v1 = (obj_num > 1);
            float m01 = v1 ? iou01 : -1.0f;
            float m11 = v1 ? iou11 : -1.0f;
            int rsp0 = (m01 > iou00) ? 1 : 0;   // first-max argmax
            int rsp1 = (m11 > iou10) ? 1 : 0;

            float s00 = 0.0f, s01 = 0.0f, s10 = 0.0f, s11 = 0.0f;
            #pragma unroll
            for (int k = 0; k < 20; ++k) {
                float pk0 = P[1 + k], pk1 = P[26 + k];
                float gk0 = G[1 + k], gk1 = G[26 + k];
                float d;
                d = pk0 - gk0; s00 += d * d;
                d = pk0 - gk1; s01 += d * d;
                d = pk1 - gk0; s10 += d * d;
                d = pk1 - gk1; s11 += d * d;
            }
            float cls0 = (rsp0 ? s01 : s00) * (1.0f / 20.0f);
            float cls1 = (rsp1 ? s11 : s10) * (1.0f / 20.0f);

            {
                float rx = rsp0 ? G[46] : G[21];
                float ry = rsp0 ? G[47] : G[22];
                float rw = rsp0 ? G[48] : G[23];
                float rh = rsp0 ? G[49] : G[24];
                float dx = P[21] - rx, dy = P[22] - ry;
                float dw = sqrtf(P[23]) - sqrtf(rw);
                float dh = sqrtf(P[24]) - sqrtf(rh);
                acc += LAMBDA_COORD * (dx * dx + dy * dy + dw * dw + dh * dh) + cls0;
            }
            {
                float rx = rsp1 ? G[46] : G[21];
                float ry = rsp1 ? G[47] : G[22];
                float rw = rsp1 ? G[48] : G[23];
                float rh = rsp1 ? G[49] : G[24];
                float dx = P[46] - rx, dy = P[47] - ry;
                float dw = sqrtf(P[48]) - sqrtf(rw);
                float dh = sqrtf(P[49]) - sqrtf(rh);
                acc += LAMBDA_COORD * (dx * dx + dy * dy + dw * dw + dh * dh) + cls1;
            }
        }
    }

    // wave reduction; one partial per block
    #pragma unroll
    for (int off = 32; off > 0; off >>= 1) acc += __shfl_down(acc, off);
    if (lane == 0) partial[blockIdx.x] = acc;
}

__global__ __launch_bounds__(256) void yolo_loss_final(
        const float* __restrict__ partial, int n, float* __restrict__ out,
        float inv_batch) {
    float acc = 0.0f;
    for (int i = threadIdx.x; i < n; i += 256) acc += partial[i];
    #pragma unroll
    for (int off = 32; off > 0; off >>= 1) acc += __shfl_down(acc, off);
    __shared__ float wsum[4];
    int lane = threadIdx.x & 63;
    int wid = threadIdx.x >> 6;
    if (lane == 0) wsum[wid] = acc;
    __syncthreads();
    if (threadIdx.x == 0) {
        out[0] = (wsum[0] + wsum[1] + wsum[2] + wsum[3]) * inv_batch;
    }
}

extern "C" void kernel_launch(void* const* d_in, const int* in_sizes, int n_in,
                              void* d_out, int out_size, void* d_ws, size_t ws_size,
                              hipStream_t stream) {
    const float4* pr4 = (const float4*)d_in[0];
    const float4* gt4 = (const float4*)d_in[1];
    float* out = (float*)d_out;
    float* partial = (float*)d_ws;

    int total_elems = in_sizes[0];            // 20,070,400
    int ncells = total_elems / CELL_F;        // 401,408
    int batch = total_elems / 2450;           // 8192
    int ntiles = ncells / TILE_CELLS;         // 6272

    int blocks = NBLOCKS < ntiles ? NBLOCKS : ntiles;
    yolo_loss_partial<<<blocks, 64, 0, stream>>>(pr4, gt4, partial, ntiles);
    yolo_loss_final<<<1, 256, 0, stream>>>(partial, blocks, out, 1.0f / (float)batch);
}